// Round 10
// baseline (489.988 us; speedup 1.0000x reference)
//
#include <hip/hip_runtime.h>
#include <stdint.h>

typedef unsigned short u16;
typedef u16   us4 __attribute__((ext_vector_type(4)));
typedef u16   us8 __attribute__((ext_vector_type(8)));
typedef __bf16 bf8 __attribute__((ext_vector_type(8)));
typedef float f4  __attribute__((ext_vector_type(4)));

__device__ __forceinline__ u16 f2bf(float f) {
    uint32_t u = __builtin_bit_cast(uint32_t, f);
    uint32_t r = (u + 0x7fffu + ((u >> 16) & 1u)) >> 16;   // RNE
    return (u16)r;
}
__device__ __forceinline__ float bf2f(u16 s) {
    uint32_t u = ((uint32_t)s) << 16;
    return __builtin_bit_cast(float, u);
}
__device__ __forceinline__ u16 cvtbf(float f) {   // native RNE cvt
    return __builtin_bit_cast(u16, (__bf16)f);
}
__device__ __forceinline__ f4 mfma16(bf8 a, bf8 b, f4 c) {
    return __builtin_amdgcn_mfma_f32_16x16x32_bf16(a, b, c, 0, 0, 0);
}
__device__ __forceinline__ u16 max4bf(u16 a, u16 b, u16 c, u16 d) {
    float m = fmaxf(fmaxf(bf2f(a), bf2f(b)), fmaxf(bf2f(c), bf2f(d)));
    return f2bf(m);   // exact: m is already a bf16 value
}

// ---------------------------------------------------------------------------
// Kernel 0a: X transpose+convert.  x[n][c][4096] fp32 -> Xt[n][s][512] bf16.
// ---------------------------------------------------------------------------
__global__ __launch_bounds__(256) void xt_kernel(
    const float* __restrict__ x, u16* __restrict__ Xt)
{
    const int s0 = blockIdx.x * 64, c0 = blockIdx.y * 64, n = blockIdx.z;
    const int tid = threadIdx.x;
    __shared__ u16 lds[64 * 72];   // [s_loc][c_loc], stride 72

    {
        int c_loc = tid & 63, s_seg = (tid >> 6) * 16;
        const float* src = x + ((size_t)n * 512 + c0 + c_loc) * 4096 + s0 + s_seg;
        for (int i4 = 0; i4 < 4; i4++) {
            float4 f = *(const float4*)(src + i4 * 4);
            int s = s_seg + i4 * 4;
            lds[(s + 0) * 72 + c_loc] = f2bf(f.x);
            lds[(s + 1) * 72 + c_loc] = f2bf(f.y);
            lds[(s + 2) * 72 + c_loc] = f2bf(f.z);
            lds[(s + 3) * 72 + c_loc] = f2bf(f.w);
        }
    }
    __syncthreads();
    {
        int s_loc = tid >> 2, c_seg = (tid & 3) * 16;
        u16* dst = Xt + ((size_t)n * 4096 + s0 + s_loc) * 512 + c0 + c_seg;
        *(us8*)(dst)     = *(const us8*)&lds[s_loc * 72 + c_seg];
        *(us8*)(dst + 8) = *(const us8*)&lds[s_loc * 72 + c_seg + 8];
    }
}

// ---------------------------------------------------------------------------
// Kernel 0b: weight convert. Wall_bf[384][512] = [theta;phi;g], Wo_bf[512][256].
// ---------------------------------------------------------------------------
__global__ __launch_bounds__(256) void wconv_kernel(
    const float* __restrict__ w_theta, const float* __restrict__ w_phi,
    const float* __restrict__ w_g, const float* __restrict__ w_o,
    u16* __restrict__ Wall_bf, u16* __restrict__ Wo_bf)
{
    int base = (blockIdx.x * 256 + threadIdx.x) * 4;   // 327680 total elems
    const float* src; u16* dst;
    if (base < 32768)       { src = w_theta + base;          dst = Wall_bf + base; }
    else if (base < 65536)  { src = w_phi + (base - 32768);  dst = Wall_bf + base; }
    else if (base < 196608) { src = w_g + (base - 65536);    dst = Wall_bf + base; }
    else                    { src = w_o + (base - 196608);   dst = Wo_bf + (base - 196608); }
    float4 f = *(const float4*)src;
    us4 v; v[0] = f2bf(f.x); v[1] = f2bf(f.y); v[2] = f2bf(f.z); v[3] = f2bf(f.w);
    *(us4*)dst = v;
}

// ---------------------------------------------------------------------------
// Kernel 1: projection GEMM (round 9: 256x128 tile, 8 waves, 1-barrier dbuf).
// Bigger tile = 0.75x staging bytes/FLOP, half the barriers per output.
// PT[n][s][384] = Xt[n][s][:512] . Wall_bf[row][:512]^T
// ---------------------------------------------------------------------------
__global__ __launch_bounds__(512) void projT_gemm(
    const u16* __restrict__ Xt, const u16* __restrict__ Wall_bf,
    u16* __restrict__ PT)
{
    const int s0 = blockIdx.x * 256;     // 16 tiles
    const int r0 = blockIdx.y * 128;     // 3 tiles (384 rows)
    const int nb = blockIdx.z;
    const int tid = threadIdx.x;
    const int wave = tid >> 6, lane = tid & 63;
    const int quad = lane >> 4, l15 = lane & 15;
    const int wm = (wave >> 1) * 64, wn = (wave & 1) * 64;   // 4x2 wave grid

    __shared__ u16 a_lds[2][256 * 40];   // [buf][s_loc][k], stride 40
    __shared__ u16 b_lds[2][128 * 40];   // [buf][row_loc][k], stride 40

    f4 acc[4][4];
    f4 z = {0.f, 0.f, 0.f, 0.f};
    for (int i = 0; i < 4; i++) for (int j = 0; j < 4; j++) acc[i][j] = z;

    const int ma = tid >> 1, ka = (tid & 1) * 16;   // A: 256 rows x 2 thr
    const int mb = tid >> 2, kb = (tid & 3) * 8;    // B: 128 rows x 4 thr
    const u16* As = Xt + ((size_t)nb * 4096 + s0 + ma) * 512 + ka;
    const u16* Bs = Wall_bf + (size_t)(r0 + mb) * 512 + kb;

    // prologue: tile 0 -> LDS[0]; tile 1 -> regs
    {
        us8 x0 = *(const us8*)(As), x1 = *(const us8*)(As + 8);
        us8 y0 = *(const us8*)(Bs);
        *(us8*)&a_lds[0][ma * 40 + ka]     = x0;
        *(us8*)&a_lds[0][ma * 40 + ka + 8] = x1;
        *(us8*)&b_lds[0][mb * 40 + kb]     = y0;
    }
    us8 pa0 = *(const us8*)(As + 32), pa1 = *(const us8*)(As + 40);
    us8 pb0 = *(const us8*)(Bs + 32);
    __syncthreads();

    for (int ci = 0; ci < 16; ci++) {
        const int buf = ci & 1;
        bf8 af[4], bfr[4];
        for (int i = 0; i < 4; i++)
            af[i]  = __builtin_bit_cast(bf8, *(const us8*)&a_lds[buf][(wm + i*16 + l15)*40 + quad*8]);
        for (int j = 0; j < 4; j++)
            bfr[j] = __builtin_bit_cast(bf8, *(const us8*)&b_lds[buf][(wn + j*16 + l15)*40 + quad*8]);
        for (int i = 0; i < 4; i++)
            for (int j = 0; j < 4; j++)
                acc[i][j] = mfma16(af[i], bfr[j], acc[i][j]);
        // write prefetched tile ci+1 -> LDS[buf^1] (vmcnt wait automatic)
        *(us8*)&a_lds[buf ^ 1][ma * 40 + ka]     = pa0;
        *(us8*)&a_lds[buf ^ 1][ma * 40 + ka + 8] = pa1;
        *(us8*)&b_lds[buf ^ 1][mb * 40 + kb]     = pb0;
        __syncthreads();
        // issue tile ci+2 loads (clamped; redundant at tail)
        const int k2 = ((ci + 2 < 16) ? ci + 2 : 15) * 32;
        pa0 = *(const us8*)(As + k2);
        pa1 = *(const us8*)(As + k2 + 8);
        pb0 = *(const us8*)(Bs + k2);
    }
    for (int i = 0; i < 4; i++) {
        int s_idx = s0 + wm + i * 16 + quad * 4;
        for (int rr = 0; rr < 4; rr++) {
            u16* dst = PT + ((size_t)nb * 4096 + s_idx + rr) * 384 + r0 + wn + l15;
            for (int j = 0; j < 4; j++)
                dst[j * 16] = f2bf(acc[i][j][rr]);
        }
    }
}

// ---------------------------------------------------------------------------
// Kernel 3: phi pool -> FRAGMENT-MAJOR output.
// phiF[((n*32 + c)*2 + tt)*1024 + kh*512 + lane*8 + e]
//   = phi[n][t = c*32 + tt*16 + (lane&15)][d = kh*32 + (lane>>4)*8 + e]
// ---------------------------------------------------------------------------
__global__ __launch_bounds__(256) void phi_pool2(
    const u16* __restrict__ PT, u16* __restrict__ phiF)
{
    int n = blockIdx.y, t0 = blockIdx.x * 64;
    int tid = threadIdx.x;
    int t_loc = tid >> 2, d0 = (tid & 3) * 16;
    int t = t0 + t_loc;
    int h2 = t >> 5, w2 = t & 31;
    int s00 = h2 * 128 + w2 * 2;
    const u16* base = PT + ((size_t)n * 4096) * 384 + 64 + d0;
    us8 r[4][2];
    int soff[4] = {s00, s00 + 1, s00 + 64, s00 + 65};
    for (int p = 0; p < 4; p++) {
        r[p][0] = *(const us8*)(base + (size_t)soff[p] * 384);
        r[p][1] = *(const us8*)(base + (size_t)soff[p] * 384 + 8);
    }
    us8 o0, o1;
    for (int i = 0; i < 8; i++) {
        o0[i] = max4bf(r[0][0][i], r[1][0][i], r[2][0][i], r[3][0][i]);   // d = d0..d0+7
        o1[i] = max4bf(r[0][1][i], r[1][1][i], r[2][1][i], r[3][1][i]);   // d = d0+8..d0+15
    }
    size_t fb = (((size_t)n * 32 + (t >> 5)) * 2 + ((t >> 4) & 1)) * 1024
              + (size_t)(d0 >> 5) * 512
              + (size_t)(((d0 >> 3) & 3) * 16 + (t & 15)) * 8;
    *(us8*)(phiF + fb)       = o0;
    *(us8*)(phiF + fb + 128) = o1;
}

// ---------------------------------------------------------------------------
// Kernel 4: g pool + transpose -> FRAGMENT-MAJOR output.
// gF[(((n*4 + w)*4 + i)*32 + c)*512 + lane*8 + e]
//   = g[n][d2 = w*64 + i*16 + (lane&15)][t = c*32 + (lane>>4)*8 + e]
// ---------------------------------------------------------------------------
__global__ __launch_bounds__(256) void g_poolT(
    const u16* __restrict__ PT, u16* __restrict__ gF)
{
    int t0 = blockIdx.x * 64, d0 = blockIdx.y * 64, n = blockIdx.z;
    int tid = threadIdx.x;
    __shared__ u16 lds[64 * 72];   // [d_loc][t_loc], stride 72

    {
        int t_loc = tid & 63, dseg = (tid >> 6) * 16;
        int t = t0 + t_loc;
        int h2 = t >> 5, w2 = t & 31;
        int s00 = h2 * 128 + w2 * 2;
        const u16* base = PT + ((size_t)n * 4096) * 384 + 128 + d0 + dseg;
        us8 r[4][2];
        int soff[4] = {s00, s00 + 1, s00 + 64, s00 + 65};
        for (int p = 0; p < 4; p++) {
            r[p][0] = *(const us8*)(base + (size_t)soff[p] * 384);
            r[p][1] = *(const us8*)(base + (size_t)soff[p] * 384 + 8);
        }
        for (int i = 0; i < 8; i++) {
            lds[(dseg + i) * 72 + t_loc]     = max4bf(r[0][0][i], r[1][0][i], r[2][0][i], r[3][0][i]);
            lds[(dseg + 8 + i) * 72 + t_loc] = max4bf(r[0][1][i], r[1][1][i], r[2][1][i], r[3][1][i]);
        }
    }
    __syncthreads();
    {
        int d_loc = tid >> 2, t_seg = (tid & 3) * 16;
        size_t fb = ((((size_t)n * 4 + blockIdx.y) * 4 + (d_loc >> 4)) * 32
                     + (t0 >> 5) + (t_seg >> 5)) * 512
                  + (size_t)((((t_seg >> 3) & 3)) * 16 + (d_loc & 15)) * 8;
        *(us8*)(gF + fb)       = *(const us8*)&lds[d_loc * 72 + t_seg];
        *(us8*)(gF + fb + 128) = *(const us8*)&lds[d_loc * 72 + t_seg + 8];
    }
}

// ---------------------------------------------------------------------------
// Kernel 5: attention (unchanged from round 5: 8-wave / 128 queries,
// LDS-staged phi, 8-way d2 split, dbuf p_lds/phi_lds, 1 barrier/chunk).
// ---------------------------------------------------------------------------
__global__ __launch_bounds__(512, 4) void attn_kernel(
    const u16* __restrict__ PT, const u16* __restrict__ phiF,
    const u16* __restrict__ gF, u16* __restrict__ yT)
{
    // bijective XCD swizzle (512 % 8 == 0): XCD k -> tiles [k*64, k*64+64)
    const int orig = blockIdx.x;
    const int tile = (orig & 7) * 64 + (orig >> 3);
    const int n = tile >> 5;             // 32 tiles of 128 q per batch
    const int q0b = (tile & 31) * 128;

    const int tid = threadIdx.x;
    const int wave = tid >> 6, lane = tid & 63, quad = lane >> 4, l15 = lane & 15;

    __shared__ u16 p_lds[2][8][16 * 40];    // [buf][q_tile][l15*40 + t]
    __shared__ u16 phi_lds[2][32 * 72];     // [buf][t*72 + d]
    __shared__ float qsum[128];

    // theta fragments (B-operand) for this wave's 16 queries
    const u16* th = PT + ((size_t)n * 4096 + q0b + wave * 16 + l15) * 384 + quad * 8;
    bf8 bth0 = __builtin_bit_cast(bf8, *(const us8*)(th));
    bf8 bth1 = __builtin_bit_cast(bf8, *(const us8*)(th + 32));

    // G fragments: wave handles d2 = wave*32 + i*16, i in {0,1}
    const u16* gbase = gF + ((size_t)n * 16 + wave * 2) * 16384 + lane * 8;

    // cooperative phi staging
    const u16* phi_src = phiF + (size_t)n * 65536 + tid * 4;
    const int sl = (tid >> 1) & 63;
    const int st = ((tid >> 8) & 1) * 16 + (sl & 15);
    const int sd = ((tid >> 7) & 1) * 32 + (sl >> 4) * 8 + (tid & 1) * 4;
    u16* pdst0 = &phi_lds[0][st * 72 + sd];
    u16* pdst1 = &phi_lds[1][st * 72 + sd];

    f4 z = {0.f, 0.f, 0.f, 0.f};
    f4 acc[2][8];
    for (int i = 0; i < 2; i++) for (int j = 0; j < 8; j++) acc[i][j] = z;
    float lsum = 0.f;

    // prologue: phi(0) -> LDS buf0; phi(1) -> reg; G(0) -> regs
    {
        us4 p0 = *(const us4*)(phi_src);
        *(us4*)pdst0 = p0;
    }
    us4 pf = *(const us4*)(phi_src + 2048);
    us8 gg0 = *(const us8*)(gbase);
    us8 gg1 = *(const us8*)(gbase + 16384);
    __syncthreads();

    for (int ci = 0; ci < 32; ci++) {
        const int buf = ci & 1;
        const u16* pl  = buf ? phi_lds[1] : phi_lds[0];
        u16* pbw = buf ? &p_lds[1][0][0] : &p_lds[0][0][0];

        // ---- QK^T from phi_lds[buf]: S^T tiles D[t][q], exp, pack ----
        for (int tt = 0; tt < 2; tt++) {
            bf8 ap0 = __builtin_bit_cast(bf8, *(const us8*)&pl[(tt * 16 + l15) * 72 + quad * 8]);
            bf8 ap1 = __builtin_bit_cast(bf8, *(const us8*)&pl[(tt * 16 + l15) * 72 + 32 + quad * 8]);
            f4 s = mfma16(ap0, bth0, z);
            s = mfma16(ap1, bth1, s);
            us4 pk; float ps = 0.f;
            for (int rr = 0; rr < 4; rr++) {
                float p = __expf(s[rr]);
                ps += p;
                pk[rr] = cvtbf(p);
            }
            lsum += ps;
            *(us4*)&pbw[wave * 640 + l15 * 40 + tt * 16 + quad * 4] = pk;
        }

        // ---- stage phi(ci+1) into buf^1 (auto vmcnt wait on pf) ----
        *(us4*)(buf ? pdst0 : pdst1) = pf;

        __syncthreads();

        // ---- issue next-chunk loads ----
        us8 ggn0, ggn1;
        {
            const int c2 = (ci + 2 < 32) ? ci + 2 : 31;
            pf = *(const us4*)(phi_src + (size_t)c2 * 2048);
            const int c1 = (ci + 1 < 32) ? ci + 1 : 31;
            ggn0 = *(const us8*)(gbase + (size_t)c1 * 512);
            ggn1 = *(const us8*)(gbase + 16384 + (size_t)c1 * 512);
        }

        // ---- PV: A=G[d2][t], B=P[q][t] -> D[d2][q]; d2 8-way wave split ----
        bf8 ag0 = __builtin_bit_cast(bf8, gg0);
        bf8 ag1 = __builtin_bit_cast(bf8, gg1);
        const u16* pbr = buf ? &p_lds[1][0][0] : &p_lds[0][0][0];
        for (int j = 0; j < 8; j++) {
            bf8 bp = __builtin_bit_cast(bf8, *(const us8*)&pbr[j * 640 + l15 * 40 + quad * 8]);
            acc[0][j] = mfma16(ag0, bp, acc[0][j]);
            acc[1][j] = mfma16(ag1, bp, acc[1][j]);
        }
        gg0 = ggn0; gg1 = ggn1;
        // no 2nd barrier: p_lds/phi_lds double-buffers make next writes safe
    }

    // softmax denominators: lane holds partial for q = wave*16+l15; sum quads
    float v = lsum;
    v += __shfl_xor(v, 16);
    v += __shfl_xor(v, 32);
    if (lane < 16) qsum[wave * 16 + lane] = v;
    __syncthreads();

    // epilogue: acc[i][j][rr] = O[d2 = wave*32+i*16+quad*4+rr][q = q0b+j*16+l15]
    for (int j = 0; j < 8; j++) {
        float invj = 1.0f / qsum[j * 16 + l15];
        u16* dst = yT + ((size_t)n * 4096 + q0b + j * 16 + l15) * 256 + wave * 32 + quad * 4;
        for (int i = 0; i < 2; i++) {
            us4 o;
            for (int rr = 0; rr < 4; rr++) o[rr] = cvtbf(acc[i][j][rr] * invj);
            *(us4*)(dst + i * 16) = o;
        }
    }
}

// ---------------------------------------------------------------------------
// Kernel 6: o-projection + residual (round 9: 128x128 tile, 1-barrier dbuf).
// out[n][c][s] = gamma * (Wo_bf[c][:] . yT[n][s][:]) + x[n][c][s]
// ---------------------------------------------------------------------------
__global__ __launch_bounds__(256) void oproj_gemm(
    const u16* __restrict__ Wo_bf, const u16* __restrict__ yT,
    const float* __restrict__ x, const float* __restrict__ gamma,
    float* __restrict__ out)
{
    const int nt = blockIdx.x;          // 0..31 (s tiles, 128 wide)
    const int mt = blockIdx.y;          // 0..3  (c tiles, 128 wide)
    const int nb = blockIdx.z;
    const int tid = threadIdx.x;
    const int wave = tid >> 6, lane = tid & 63;
    const int quad = lane >> 4, l15 = lane & 15;
    const int wm = (wave >> 1) * 64, wn = (wave & 1) * 64;   // 2x2 wave grid
    const int s0 = nt * 128;

    __shared__ u16 a_lds[2][128 * 40];
    __shared__ u16 b_lds[2][128 * 40];

    f4 acc[4][4];
    f4 z = {0.f, 0.f, 0.f, 0.f};
    for (int i = 0; i < 4; i++) for (int j = 0; j < 4; j++) acc[i][j] = z;

    const int m = tid >> 1, kq = (tid & 1) * 16;
    const u16* As = Wo_bf + (size_t)(mt * 128 + m) * 256 + kq;
    const u16* Bs = yT + ((size_t)nb * 4096 + s0 + m) * 256 + kq;

    // prologue: tile 0 -> LDS[0]; tile 1 -> regs
    {
        us8 a0 = *(const us8*)(As), a1 = *(const us8*)(As + 8);
        us8 b0 = *(const us8*)(Bs), b1 = *(const us8*)(Bs + 8);
        *(us8*)&a_lds[0][m * 40 + kq]     = a0;
        *(us8*)&a_lds[0][m * 40 + kq + 8] = a1;
        *(us8*)&b_lds[0][m * 40 + kq]     = b0;
        *(us8*)&b_lds[0][m * 40 + kq + 8] = b1;
    }
    us8 pa0 = *(const us8*)(As + 32), pa1 = *(const us8*)(As + 40);
    us8 pb0 = *(const us8*)(Bs + 32), pb1 = *(const us8*)(Bs + 40);
    __syncthreads();

    for (int ci = 0; ci < 8; ci++) {
        const int buf = ci & 1;
        bf8 af[4], bfr[4];
        for (int i = 0; i < 4; i++)
            af[i] = __builtin_bit_cast(bf8, *(const us8*)&a_lds[buf][(wm + i*16 + l15)*40 + quad*8]);
        for (int j = 0; j < 4; j++)
            bfr[j] = __builtin_bit_cast(bf8, *(const us8*)&b_lds[buf][(wn + j*16 + l15)*40 + quad*8]);
        for (int i = 0; i < 4; i++)
            for (int j = 0; j < 4; j++)
                acc[i][j] = mfma16(af[i], bfr[j], acc[i][j]);
        // write prefetched tile ci+1 -> LDS[buf^1]
        *(us8*)&a_lds[buf ^ 1][m * 40 + kq]     = pa0;
        *(us8*)&a_lds[buf ^ 1][m * 40 + kq + 8] = pa1;
        *(us8*)&b_lds[buf ^ 1][m * 40 + kq]     = pb0;
        *(us8*)&b_lds[buf ^ 1][m * 40 + kq + 8] = pb1;
        __syncthreads();
        const int k2 = ((ci + 2 < 8) ? ci + 2 : 7) * 32;
        pa0 = *(const us8*)(As + k2);
        pa1 = *(const us8*)(As + k2 + 8);
        pb0 = *(const us8*)(Bs + k2);
        pb1 = *(const us8*)(Bs + k2 + 8);
    }
    float g0 = gamma[0];
    for (int i = 0; i < 4; i++) {
        int c = mt * 128 + wm + i * 16 + quad * 4;
        for (int j = 0; j < 4; j++) {
            int s = s0 + wn + j * 16 + l15;
            for (int rr = 0; rr < 4; rr++) {
                size_t idx = ((size_t)nb * 512 + c + rr) * 4096 + s;
                out[idx] = g0 * acc[i][j][rr] + x[idx];
            }
        }
    }
}

// ---------------------------------------------------------------------------
// Workspace layout (bytes). Xt region is dead after projT_gemm, so yT/phiF/gF
// overlay it. Total = 118,095,872 B (~113 MB).
// ---------------------------------------------------------------------------
extern "C" void kernel_launch(void* const* d_in, const int* in_sizes, int n_in,
                              void* d_out, int out_size, void* d_ws, size_t ws_size,
                              hipStream_t stream)
{
    (void)in_sizes; (void)n_in; (void)out_size; (void)ws_size;
    const float* x       = (const float*)d_in[0];
    const float* w_theta = (const float*)d_in[1];
    const float* w_phi   = (const float*)d_in[2];
    const float* w_g     = (const float*)d_in[3];
    const float* w_o     = (const float*)d_in[4];
    const float* gamma   = (const float*)d_in[5];
    float* out = (float*)d_out;

    char* ws = (char*)d_ws;
    u16* Xt      = (u16*)(ws);
    u16* yT      = (u16*)(ws);                 // overlays Xt (dead by then)
    u16* phiF    = (u16*)(ws + 33554432);      // overlays Xt
    u16* gF      = (u16*)(ws + 35651584);      // overlays Xt
    u16* Wall_bf = (u16*)(ws + 67108864);
    u16* Wo_bf   = (u16*)(ws + 67502080);
    u16* PT      = (u16*)(ws + 67764224);

    xt_kernel  <<<dim3(64, 8, 16), 256, 0, stream>>>(x, Xt);
    wconv_kernel<<<320, 256, 0, stream>>>(w_theta, w_phi, w_g, w_o, Wall_bf, Wo_bf);
    projT_gemm <<<dim3(16, 3, 16), 512, 0, stream>>>(Xt, Wall_bf, PT);
    phi_pool2  <<<dim3(16, 16),    256, 0, stream>>>(PT, phiF);
    g_poolT    <<<dim3(16, 4, 16), 256, 0, stream>>>(PT, gF);
    attn_kernel<<<dim3(512),       512, 0, stream>>>(PT, phiF, gF, yT);
    oproj_gemm <<<dim3(32, 4, 16), 256, 0, stream>>>(Wo_bf, yT, x, gamma, out);
}

// Round 13
// 392.464 us; speedup vs baseline: 1.2485x; 1.2485x over previous
//
#include <hip/hip_runtime.h>
#include <stdint.h>

typedef unsigned short u16;
typedef u16   us4 __attribute__((ext_vector_type(4)));
typedef u16   us8 __attribute__((ext_vector_type(8)));
typedef __bf16 bf8 __attribute__((ext_vector_type(8)));
typedef float f4  __attribute__((ext_vector_type(4)));

__device__ __forceinline__ u16 f2bf(float f) {
    uint32_t u = __builtin_bit_cast(uint32_t, f);
    uint32_t r = (u + 0x7fffu + ((u >> 16) & 1u)) >> 16;   // RNE
    return (u16)r;
}
__device__ __forceinline__ float bf2f(u16 s) {
    uint32_t u = ((uint32_t)s) << 16;
    return __builtin_bit_cast(float, u);
}
__device__ __forceinline__ u16 cvtbf(float f) {   // native RNE cvt
    return __builtin_bit_cast(u16, (__bf16)f);
}
__device__ __forceinline__ f4 mfma16(bf8 a, bf8 b, f4 c) {
    return __builtin_amdgcn_mfma_f32_16x16x32_bf16(a, b, c, 0, 0, 0);
}
__device__ __forceinline__ u16 max4bf(u16 a, u16 b, u16 c, u16 d) {
    float m = fmaxf(fmaxf(bf2f(a), bf2f(b)), fmaxf(bf2f(c), bf2f(d)));
    return f2bf(m);   // exact: m is already a bf16 value
}

// ---------------------------------------------------------------------------
// Kernel 0a: X transpose+convert.  x[n][c][4096] fp32 -> Xt[n][s][512] bf16.
// ---------------------------------------------------------------------------
__global__ __launch_bounds__(256) void xt_kernel(
    const float* __restrict__ x, u16* __restrict__ Xt)
{
    const int s0 = blockIdx.x * 64, c0 = blockIdx.y * 64, n = blockIdx.z;
    const int tid = threadIdx.x;
    __shared__ u16 lds[64 * 72];   // [s_loc][c_loc], stride 72

    {
        int c_loc = tid & 63, s_seg = (tid >> 6) * 16;
        const float* src = x + ((size_t)n * 512 + c0 + c_loc) * 4096 + s0 + s_seg;
        for (int i4 = 0; i4 < 4; i4++) {
            float4 f = *(const float4*)(src + i4 * 4);
            int s = s_seg + i4 * 4;
            lds[(s + 0) * 72 + c_loc] = f2bf(f.x);
            lds[(s + 1) * 72 + c_loc] = f2bf(f.y);
            lds[(s + 2) * 72 + c_loc] = f2bf(f.z);
            lds[(s + 3) * 72 + c_loc] = f2bf(f.w);
        }
    }
    __syncthreads();
    {
        int s_loc = tid >> 2, c_seg = (tid & 3) * 16;
        u16* dst = Xt + ((size_t)n * 4096 + s0 + s_loc) * 512 + c0 + c_seg;
        *(us8*)(dst)     = *(const us8*)&lds[s_loc * 72 + c_seg];
        *(us8*)(dst + 8) = *(const us8*)&lds[s_loc * 72 + c_seg + 8];
    }
}

// ---------------------------------------------------------------------------
// Kernel 0b: weight convert. Wall_bf[384][512] = [theta;phi;g], Wo_bf[512][256].
// ---------------------------------------------------------------------------
__global__ __launch_bounds__(256) void wconv_kernel(
    const float* __restrict__ w_theta, const float* __restrict__ w_phi,
    const float* __restrict__ w_g, const float* __restrict__ w_o,
    u16* __restrict__ Wall_bf, u16* __restrict__ Wo_bf)
{
    int base = (blockIdx.x * 256 + threadIdx.x) * 4;   // 327680 total elems
    const float* src; u16* dst;
    if (base < 32768)       { src = w_theta + base;          dst = Wall_bf + base; }
    else if (base < 65536)  { src = w_phi + (base - 32768);  dst = Wall_bf + base; }
    else if (base < 196608) { src = w_g + (base - 65536);    dst = Wall_bf + base; }
    else                    { src = w_o + (base - 196608);   dst = Wo_bf + (base - 196608); }
    float4 f = *(const float4*)src;
    us4 v; v[0] = f2bf(f.x); v[1] = f2bf(f.y); v[2] = f2bf(f.z); v[3] = f2bf(f.w);
    *(us4*)dst = v;
}

// ---------------------------------------------------------------------------
// Kernel 1: projection GEMM (round-8 verified: 128x128, 4 waves,
// 1-barrier double-buffer + 2-deep reg prefetch).
// Round-10 lesson: 256x128/8-wave regressed (register pressure + fewer
// blocks); this shape measured 395us e2e.
// PT[n][s][384] = Xt[n][s][:512] . Wall_bf[row][:512]^T
// ---------------------------------------------------------------------------
__global__ __launch_bounds__(256) void projT_gemm(
    const u16* __restrict__ Xt, const u16* __restrict__ Wall_bf,
    u16* __restrict__ PT)
{
    const int s0 = blockIdx.x * 128;     // 32 tiles
    const int r0 = blockIdx.y * 128;     // 3 tiles (384 rows)
    const int nb = blockIdx.z;
    const int tid = threadIdx.x;
    const int wave = tid >> 6, lane = tid & 63;
    const int quad = lane >> 4, l15 = lane & 15;
    const int wm = (wave >> 1) * 64, wn = (wave & 1) * 64;

    __shared__ u16 a_lds[2][128 * 40];   // [buf][s_loc][k], stride 40
    __shared__ u16 b_lds[2][128 * 40];   // [buf][row_loc][k], stride 40

    f4 acc[4][4];
    f4 z = {0.f, 0.f, 0.f, 0.f};
    for (int i = 0; i < 4; i++) for (int j = 0; j < 4; j++) acc[i][j] = z;

    const int m = tid >> 1, kseg = (tid & 1) * 16;
    const u16* As = Xt + ((size_t)nb * 4096 + s0 + m) * 512 + kseg;
    const u16* Bs = Wall_bf + (size_t)(r0 + m) * 512 + kseg;

    // prologue: tile 0 -> LDS[0]; tile 1 -> regs
    {
        us8 x0 = *(const us8*)(As), x1 = *(const us8*)(As + 8);
        us8 y0 = *(const us8*)(Bs), y1 = *(const us8*)(Bs + 8);
        *(us8*)&a_lds[0][m * 40 + kseg]     = x0;
        *(us8*)&a_lds[0][m * 40 + kseg + 8] = x1;
        *(us8*)&b_lds[0][m * 40 + kseg]     = y0;
        *(us8*)&b_lds[0][m * 40 + kseg + 8] = y1;
    }
    us8 pa0 = *(const us8*)(As + 32), pa1 = *(const us8*)(As + 40);
    us8 pb0 = *(const us8*)(Bs + 32), pb1 = *(const us8*)(Bs + 40);
    __syncthreads();

    for (int ci = 0; ci < 16; ci++) {
        const int buf = ci & 1;
        // compute tile ci from LDS[buf]
        bf8 af[4], bfr[4];
        for (int i = 0; i < 4; i++)
            af[i]  = __builtin_bit_cast(bf8, *(const us8*)&a_lds[buf][(wm + i*16 + l15)*40 + quad*8]);
        for (int j = 0; j < 4; j++)
            bfr[j] = __builtin_bit_cast(bf8, *(const us8*)&b_lds[buf][(wn + j*16 + l15)*40 + quad*8]);
        for (int i = 0; i < 4; i++)
            for (int j = 0; j < 4; j++)
                acc[i][j] = mfma16(af[i], bfr[j], acc[i][j]);
        // write prefetched tile ci+1 -> LDS[buf^1] (vmcnt wait is automatic)
        *(us8*)&a_lds[buf ^ 1][m * 40 + kseg]     = pa0;
        *(us8*)&a_lds[buf ^ 1][m * 40 + kseg + 8] = pa1;
        *(us8*)&b_lds[buf ^ 1][m * 40 + kseg]     = pb0;
        *(us8*)&b_lds[buf ^ 1][m * 40 + kseg + 8] = pb1;
        __syncthreads();
        // issue tile ci+2 loads (clamped; redundant at tail)
        const int k2 = ((ci + 2 < 16) ? ci + 2 : 15) * 32;
        pa0 = *(const us8*)(As + k2);
        pa1 = *(const us8*)(As + k2 + 8);
        pb0 = *(const us8*)(Bs + k2);
        pb1 = *(const us8*)(Bs + k2 + 8);
    }
    for (int i = 0; i < 4; i++) {
        int s_idx = s0 + wm + i * 16 + quad * 4;
        for (int rr = 0; rr < 4; rr++) {
            u16* dst = PT + ((size_t)nb * 4096 + s_idx + rr) * 384 + r0 + wn + l15;
            for (int j = 0; j < 4; j++)
                dst[j * 16] = f2bf(acc[i][j][rr]);
        }
    }
}

// ---------------------------------------------------------------------------
// Kernel 3: phi pool -> FRAGMENT-MAJOR output.
// phiF[((n*32 + c)*2 + tt)*1024 + kh*512 + lane*8 + e]
//   = phi[n][t = c*32 + tt*16 + (lane&15)][d = kh*32 + (lane>>4)*8 + e]
// ---------------------------------------------------------------------------
__global__ __launch_bounds__(256) void phi_pool2(
    const u16* __restrict__ PT, u16* __restrict__ phiF)
{
    int n = blockIdx.y, t0 = blockIdx.x * 64;
    int tid = threadIdx.x;
    int t_loc = tid >> 2, d0 = (tid & 3) * 16;
    int t = t0 + t_loc;
    int h2 = t >> 5, w2 = t & 31;
    int s00 = h2 * 128 + w2 * 2;
    const u16* base = PT + ((size_t)n * 4096) * 384 + 64 + d0;
    us8 r[4][2];
    int soff[4] = {s00, s00 + 1, s00 + 64, s00 + 65};
    for (int p = 0; p < 4; p++) {
        r[p][0] = *(const us8*)(base + (size_t)soff[p] * 384);
        r[p][1] = *(const us8*)(base + (size_t)soff[p] * 384 + 8);
    }
    us8 o0, o1;
    for (int i = 0; i < 8; i++) {
        o0[i] = max4bf(r[0][0][i], r[1][0][i], r[2][0][i], r[3][0][i]);   // d = d0..d0+7
        o1[i] = max4bf(r[0][1][i], r[1][1][i], r[2][1][i], r[3][1][i]);   // d = d0+8..d0+15
    }
    size_t fb = (((size_t)n * 32 + (t >> 5)) * 2 + ((t >> 4) & 1)) * 1024
              + (size_t)(d0 >> 5) * 512
              + (size_t)(((d0 >> 3) & 3) * 16 + (t & 15)) * 8;
    *(us8*)(phiF + fb)       = o0;
    *(us8*)(phiF + fb + 128) = o1;
}

// ---------------------------------------------------------------------------
// Kernel 4: g pool + transpose -> FRAGMENT-MAJOR output.
// gF[(((n*4 + w)*4 + i)*32 + c)*512 + lane*8 + e]
//   = g[n][d2 = w*64 + i*16 + (lane&15)][t = c*32 + (lane>>4)*8 + e]
// ---------------------------------------------------------------------------
__global__ __launch_bounds__(256) void g_poolT(
    const u16* __restrict__ PT, u16* __restrict__ gF)
{
    int t0 = blockIdx.x * 64, d0 = blockIdx.y * 64, n = blockIdx.z;
    int tid = threadIdx.x;
    __shared__ u16 lds[64 * 72];   // [d_loc][t_loc], stride 72

    {
        int t_loc = tid & 63, dseg = (tid >> 6) * 16;
        int t = t0 + t_loc;
        int h2 = t >> 5, w2 = t & 31;
        int s00 = h2 * 128 + w2 * 2;
        const u16* base = PT + ((size_t)n * 4096) * 384 + 128 + d0 + dseg;
        us8 r[4][2];
        int soff[4] = {s00, s00 + 1, s00 + 64, s00 + 65};
        for (int p = 0; p < 4; p++) {
            r[p][0] = *(const us8*)(base + (size_t)soff[p] * 384);
            r[p][1] = *(const us8*)(base + (size_t)soff[p] * 384 + 8);
        }
        for (int i = 0; i < 8; i++) {
            lds[(dseg + i) * 72 + t_loc]     = max4bf(r[0][0][i], r[1][0][i], r[2][0][i], r[3][0][i]);
            lds[(dseg + 8 + i) * 72 + t_loc] = max4bf(r[0][1][i], r[1][1][i], r[2][1][i], r[3][1][i]);
        }
    }
    __syncthreads();
    {
        int d_loc = tid >> 2, t_seg = (tid & 3) * 16;
        size_t fb = ((((size_t)n * 4 + blockIdx.y) * 4 + (d_loc >> 4)) * 32
                     + (t0 >> 5) + (t_seg >> 5)) * 512
                  + (size_t)((((t_seg >> 3) & 3)) * 16 + (d_loc & 15)) * 8;
        *(us8*)(gF + fb)       = *(const us8*)&lds[d_loc * 72 + t_seg];
        *(us8*)(gF + fb + 128) = *(const us8*)&lds[d_loc * 72 + t_seg + 8];
    }
}

// ---------------------------------------------------------------------------
// Kernel 5: attention (unchanged round-5 structure: 8-wave / 128 queries,
// LDS-staged phi, 8-way d2 split, dbuf p_lds/phi_lds, 1 barrier/chunk).
// ---------------------------------------------------------------------------
__global__ __launch_bounds__(512, 4) void attn_kernel(
    const u16* __restrict__ PT, const u16* __restrict__ phiF,
    const u16* __restrict__ gF, u16* __restrict__ yT)
{
    // bijective XCD swizzle (512 % 8 == 0): XCD k -> tiles [k*64, k*64+64)
    const int orig = blockIdx.x;
    const int tile = (orig & 7) * 64 + (orig >> 3);
    const int n = tile >> 5;             // 32 tiles of 128 q per batch
    const int q0b = (tile & 31) * 128;

    const int tid = threadIdx.x;
    const int wave = tid >> 6, lane = tid & 63, quad = lane >> 4, l15 = lane & 15;

    __shared__ u16 p_lds[2][8][16 * 40];    // [buf][q_tile][l15*40 + t]
    __shared__ u16 phi_lds[2][32 * 72];     // [buf][t*72 + d]
    __shared__ float qsum[128];

    // theta fragments (B-operand) for this wave's 16 queries
    const u16* th = PT + ((size_t)n * 4096 + q0b + wave * 16 + l15) * 384 + quad * 8;
    bf8 bth0 = __builtin_bit_cast(bf8, *(const us8*)(th));
    bf8 bth1 = __builtin_bit_cast(bf8, *(const us8*)(th + 32));

    // G fragments: wave handles d2 = wave*32 + i*16, i in {0,1}
    const u16* gbase = gF + ((size_t)n * 16 + wave * 2) * 16384 + lane * 8;

    // cooperative phi staging
    const u16* phi_src = phiF + (size_t)n * 65536 + tid * 4;
    const int sl = (tid >> 1) & 63;
    const int st = ((tid >> 8) & 1) * 16 + (sl & 15);
    const int sd = ((tid >> 7) & 1) * 32 + (sl >> 4) * 8 + (tid & 1) * 4;
    u16* pdst0 = &phi_lds[0][st * 72 + sd];
    u16* pdst1 = &phi_lds[1][st * 72 + sd];

    f4 z = {0.f, 0.f, 0.f, 0.f};
    f4 acc[2][8];
    for (int i = 0; i < 2; i++) for (int j = 0; j < 8; j++) acc[i][j] = z;
    float lsum = 0.f;

    // prologue: phi(0) -> LDS buf0; phi(1) -> reg; G(0) -> regs
    {
        us4 p0 = *(const us4*)(phi_src);
        *(us4*)pdst0 = p0;
    }
    us4 pf = *(const us4*)(phi_src + 2048);
    us8 gg0 = *(const us8*)(gbase);
    us8 gg1 = *(const us8*)(gbase + 16384);
    __syncthreads();

    for (int ci = 0; ci < 32; ci++) {
        const int buf = ci & 1;
        const u16* pl  = buf ? phi_lds[1] : phi_lds[0];
        u16* pbw = buf ? &p_lds[1][0][0] : &p_lds[0][0][0];

        // ---- QK^T from phi_lds[buf]: S^T tiles D[t][q], exp, pack ----
        for (int tt = 0; tt < 2; tt++) {
            bf8 ap0 = __builtin_bit_cast(bf8, *(const us8*)&pl[(tt * 16 + l15) * 72 + quad * 8]);
            bf8 ap1 = __builtin_bit_cast(bf8, *(const us8*)&pl[(tt * 16 + l15) * 72 + 32 + quad * 8]);
            f4 s = mfma16(ap0, bth0, z);
            s = mfma16(ap1, bth1, s);
            us4 pk; float ps = 0.f;
            for (int rr = 0; rr < 4; rr++) {
                float p = __expf(s[rr]);
                ps += p;
                pk[rr] = cvtbf(p);
            }
            lsum += ps;
            *(us4*)&pbw[wave * 640 + l15 * 40 + tt * 16 + quad * 4] = pk;
        }

        // ---- stage phi(ci+1) into buf^1 (auto vmcnt wait on pf) ----
        *(us4*)(buf ? pdst0 : pdst1) = pf;

        __syncthreads();

        // ---- issue next-chunk loads ----
        us8 ggn0, ggn1;
        {
            const int c2 = (ci + 2 < 32) ? ci + 2 : 31;
            pf = *(const us4*)(phi_src + (size_t)c2 * 2048);
            const int c1 = (ci + 1 < 32) ? ci + 1 : 31;
            ggn0 = *(const us8*)(gbase + (size_t)c1 * 512);
            ggn1 = *(const us8*)(gbase + 16384 + (size_t)c1 * 512);
        }

        // ---- PV: A=G[d2][t], B=P[q][t] -> D[d2][q]; d2 8-way wave split ----
        bf8 ag0 = __builtin_bit_cast(bf8, gg0);
        bf8 ag1 = __builtin_bit_cast(bf8, gg1);
        const u16* pbr = buf ? &p_lds[1][0][0] : &p_lds[0][0][0];
        for (int j = 0; j < 8; j++) {
            bf8 bp = __builtin_bit_cast(bf8, *(const us8*)&pbr[j * 640 + l15 * 40 + quad * 8]);
            acc[0][j] = mfma16(ag0, bp, acc[0][j]);
            acc[1][j] = mfma16(ag1, bp, acc[1][j]);
        }
        gg0 = ggn0; gg1 = ggn1;
        // no 2nd barrier: p_lds/phi_lds double-buffers make next writes safe
    }

    // softmax denominators: lane holds partial for q = wave*16+l15; sum quads
    float v = lsum;
    v += __shfl_xor(v, 16);
    v += __shfl_xor(v, 32);
    if (lane < 16) qsum[wave * 16 + lane] = v;
    __syncthreads();

    // epilogue: acc[i][j][rr] = O[d2 = wave*32+i*16+quad*4+rr][q = q0b+j*16+l15]
    for (int j = 0; j < 8; j++) {
        float invj = 1.0f / qsum[j * 16 + l15];
        u16* dst = yT + ((size_t)n * 4096 + q0b + j * 16 + l15) * 256 + wave * 32 + quad * 4;
        for (int i = 0; i < 2; i++) {
            us4 o;
            for (int rr = 0; rr < 4; rr++) o[rr] = cvtbf(acc[i][j][rr] * invj);
            *(us4*)(dst + i * 16) = o;
        }
    }
}

// ---------------------------------------------------------------------------
// Kernel 6: o-projection + residual (round-8 verified: 64x128,
// 1-barrier dbuf). Round-10 lesson: 128x128 hit the VGPR cliff (80 regs =
// acc+prefetch exactly -> spills, 140us).
// out[n][c][s] = gamma * (Wo_bf[c][:] . yT[n][s][:]) + x[n][c][s]
// ---------------------------------------------------------------------------
__global__ __launch_bounds__(256) void oproj_gemm(
    const u16* __restrict__ Wo_bf, const u16* __restrict__ yT,
    const float* __restrict__ x, const float* __restrict__ gamma,
    float* __restrict__ out)
{
    const int nt = blockIdx.x;          // 0..31 (s tiles)
    const int mt = blockIdx.y;          // 0..7  (c tiles)
    const int nb = blockIdx.z;
    const int tid = threadIdx.x;
    const int wave = tid >> 6, lane = tid & 63;
    const int quad = lane >> 4, l15 = lane & 15;
    const int wm = (wave >> 1) * 32, wn = (wave & 1) * 64;
    const int s0 = nt * 128;

    __shared__ u16 a_lds[2][64 * 40];
    __shared__ u16 b_lds[2][128 * 40];

    f4 acc[2][4];
    f4 z = {0.f, 0.f, 0.f, 0.f};
    for (int i = 0; i < 2; i++) for (int j = 0; j < 4; j++) acc[i][j] = z;

    const int ma = tid >> 2, kqa = (tid & 3) * 8;
    const int mb = tid >> 1, kqb = (tid & 1) * 16;
    const u16* As = Wo_bf + (size_t)(mt * 64 + ma) * 256 + kqa;
    const u16* Bs = yT + ((size_t)nb * 4096 + s0 + mb) * 256 + kqb;

    // prologue: tile 0 -> LDS[0]; tile 1 -> regs
    {
        us8 a0 = *(const us8*)(As);
        us8 b0 = *(const us8*)(Bs), b1 = *(const us8*)(Bs + 8);
        *(us8*)&a_lds[0][ma * 40 + kqa]     = a0;
        *(us8*)&b_lds[0][mb * 40 + kqb]     = b0;
        *(us8*)&b_lds[0][mb * 40 + kqb + 8] = b1;
    }
    us8 pa = *(const us8*)(As + 32);
    us8 pb0 = *(const us8*)(Bs + 32), pb1 = *(const us8*)(Bs + 40);
    __syncthreads();

    for (int ci = 0; ci < 8; ci++) {
        const int buf = ci & 1;
        bf8 af[2], bfr[4];
        for (int i = 0; i < 2; i++)
            af[i] = __builtin_bit_cast(bf8, *(const us8*)&a_lds[buf][(wm + i*16 + l15)*40 + quad*8]);
        for (int j = 0; j < 4; j++)
            bfr[j] = __builtin_bit_cast(bf8, *(const us8*)&b_lds[buf][(wn + j*16 + l15)*40 + quad*8]);
        for (int i = 0; i < 2; i++)
            for (int j = 0; j < 4; j++)
                acc[i][j] = mfma16(af[i], bfr[j], acc[i][j]);
        // write prefetched tile ci+1 -> LDS[buf^1]
        *(us8*)&a_lds[buf ^ 1][ma * 40 + kqa]     = pa;
        *(us8*)&b_lds[buf ^ 1][mb * 40 + kqb]     = pb0;
        *(us8*)&b_lds[buf ^ 1][mb * 40 + kqb + 8] = pb1;
        __syncthreads();
        const int k2 = ((ci + 2 < 8) ? ci + 2 : 7) * 32;
        pa  = *(const us8*)(As + k2);
        pb0 = *(const us8*)(Bs + k2);
        pb1 = *(const us8*)(Bs + k2 + 8);
    }
    float g0 = gamma[0];
    for (int i = 0; i < 2; i++) {
        int c = mt * 64 + wm + i * 16 + quad * 4;
        for (int j = 0; j < 4; j++) {
            int s = s0 + wn + j * 16 + l15;
            for (int rr = 0; rr < 4; rr++) {
                size_t idx = ((size_t)nb * 512 + c + rr) * 4096 + s;
                out[idx] = g0 * acc[i][j][rr] + x[idx];
            }
        }
    }
}

// ---------------------------------------------------------------------------
// Workspace layout (bytes). Xt region is dead after projT_gemm, so yT/phiF/gF
// overlay it. Total = 118,095,872 B (~113 MB).
// ---------------------------------------------------------------------------
extern "C" void kernel_launch(void* const* d_in, const int* in_sizes, int n_in,
                              void* d_out, int out_size, void* d_ws, size_t ws_size,
                              hipStream_t stream)
{
    (void)in_sizes; (void)n_in; (void)out_size; (void)ws_size;
    const float* x       = (const float*)d_in[0];
    const float* w_theta = (const float*)d_in[1];
    const float* w_phi   = (const float*)d_in[2];
    const float* w_g     = (const float*)d_in[3];
    const float* w_o     = (const float*)d_in[4];
    const float* gamma   = (const float*)d_in[5];
    float* out = (float*)d_out;

    char* ws = (char*)d_ws;
    u16* Xt      = (u16*)(ws);
    u16* yT      = (u16*)(ws);                 // overlays Xt (dead by then)
    u16* phiF    = (u16*)(ws + 33554432);      // overlays Xt
    u16* gF      = (u16*)(ws + 35651584);      // overlays Xt
    u16* Wall_bf = (u16*)(ws + 67108864);
    u16* Wo_bf   = (u16*)(ws + 67502080);
    u16* PT      = (u16*)(ws + 67764224);

    xt_kernel  <<<dim3(64, 8, 16), 256, 0, stream>>>(x, Xt);
    wconv_kernel<<<320, 256, 0, stream>>>(w_theta, w_phi, w_g, w_o, Wall_bf, Wo_bf);
    projT_gemm <<<dim3(32, 3, 16), 256, 0, stream>>>(Xt, Wall_bf, PT);
    phi_pool2  <<<dim3(16, 16),    256, 0, stream>>>(PT, phiF);
    g_poolT    <<<dim3(16, 4, 16), 256, 0, stream>>>(PT, gF);
    attn_kernel<<<dim3(512),       512, 0, stream>>>(PT, phiF, gF, yT);
    oproj_gemm <<<dim3(32, 8, 16), 256, 0, stream>>>(Wo_bf, yT, x, gamma, out);
}